// Round 8
// baseline (664.889 us; speedup 1.0000x reference)
//
#include <hip/hip_runtime.h>
#include <math.h>

#define T_TOK 8192
#define HID 1024
#define FFN_DIM 4096
#define NEXP 8
#define BM 128
#define MAX_TILES 136   // 8 * 17
#define SLOTB 16384     // one ring slot: A 128x32 bf16 (8K) + B 128x32 bf16 (8K)

typedef __attribute__((ext_vector_type(8))) __bf16 bf16x8;
typedef __attribute__((ext_vector_type(8))) unsigned short ushort8;
typedef __attribute__((ext_vector_type(4))) float f32x4;

static __device__ __forceinline__ unsigned short f2bf(float f) {
  unsigned u = __builtin_bit_cast(unsigned, f);
  u += 0x7FFFu + ((u >> 16) & 1u);
  return (unsigned short)(u >> 16);
}

static __device__ __forceinline__ void gl16(const void* g, void* l) {
  __builtin_amdgcn_global_load_lds((const __attribute__((address_space(1))) unsigned int*)g,
                                   (__attribute__((address_space(3))) unsigned int*)l,
                                   16, 0, 0);
}

static __device__ __forceinline__ ushort8 cvt8(const float* p) {
  float4 a = *(const float4*)p, b = *(const float4*)(p + 4);
  ushort8 o;
  o[0] = f2bf(a.x); o[1] = f2bf(a.y); o[2] = f2bf(a.z); o[3] = f2bf(a.w);
  o[4] = f2bf(b.x); o[5] = f2bf(b.y); o[6] = f2bf(b.z); o[7] = f2bf(b.w);
  return o;
}

// ---------------- weight conversion ----------------
__global__ void moe_cvt_w(const float* __restrict__ w1, const float* __restrict__ w2,
                          unsigned short* __restrict__ w1b, unsigned short* __restrict__ w2b) {
  size_t i = ((size_t)blockIdx.x * 256 + threadIdx.x) * 8;
  if (blockIdx.y == 0) *(ushort8*)(w1b + i) = cvt8(w1 + i);
  else                 *(ushort8*)(w2b + i) = cvt8(w2 + i);
}

// ---------------- router: one wave per token, f64 dots, f32 softmax; also emits xb ----------------
__global__ void moe_router(const float* __restrict__ x, const float* __restrict__ rw,
                           int* __restrict__ tok_idx, float* __restrict__ tok_w,
                           float* __restrict__ pbuf, unsigned short* __restrict__ xb) {
  int t = blockIdx.x * 4 + (threadIdx.x >> 6);
  int lane = threadIdx.x & 63;
  const float* xr = x + (size_t)t * HID;
  unsigned short* xbr = xb + (size_t)t * HID;
  double acc[NEXP];
#pragma unroll
  for (int e = 0; e < NEXP; ++e) acc[e] = 0.0;
  for (int i = 0; i < HID / 64; ++i) {
    float xv = xr[lane + 64 * i];
    xbr[lane + 64 * i] = f2bf(xv);
#pragma unroll
    for (int e = 0; e < NEXP; ++e)
      acc[e] += (double)xv * (double)rw[e * HID + lane + 64 * i];
  }
#pragma unroll
  for (int off = 32; off; off >>= 1)
#pragma unroll
    for (int e = 0; e < NEXP; ++e) acc[e] += __shfl_xor(acc[e], off);
  if (lane == 0) {
    double m = acc[0];
#pragma unroll
    for (int e = 1; e < NEXP; ++e) m = acc[e] > m ? acc[e] : m;
    float pf[NEXP], s = 0.0f;
#pragma unroll
    for (int e = 0; e < NEXP; ++e) { pf[e] = expf((float)(acc[e] - m)); s += pf[e]; }
    int i0 = 0;
#pragma unroll
    for (int e = 1; e < NEXP; ++e) if (acc[e] > acc[i0]) i0 = e;
    int i1 = (i0 == 0) ? 1 : 0;
#pragma unroll
    for (int e = 0; e < NEXP; ++e) if (e != i0 && acc[e] > acc[i1]) i1 = e;
    float w0 = pf[i0], w1 = pf[i1], wsum = w0 + w1;
    tok_idx[2 * t] = i0; tok_idx[2 * t + 1] = i1;
    tok_w[2 * t] = w0 / wsum; tok_w[2 * t + 1] = w1 / wsum;
    float inv = 1.0f / s;
#pragma unroll
    for (int e = 0; e < NEXP; ++e) pbuf[(size_t)t * NEXP + e] = pf[e] * inv;
  }
}

// ---------------- deterministic compaction: one 1024-thread block per expert ----------------
__global__ void moe_scatter(const int* __restrict__ tok_idx, const float* __restrict__ tok_w,
                            int* __restrict__ cursor, int* __restrict__ list,
                            float* __restrict__ listw) {
  const int e = blockIdx.x;
  __shared__ int wsum[16];
  __shared__ int base;
  const int tid = threadIdx.x, lane = tid & 63, wv = tid >> 6;
  if (tid == 0) base = 0;
  __syncthreads();
  for (int c = 0; c < 2 * T_TOK; c += 1024) {
    int i = c + tid;
    int m = (tok_idx[i] == e) ? 1 : 0;
    unsigned long long bal = __ballot(m);
    if (lane == 0) wsum[wv] = __popcll(bal);
    __syncthreads();
    int wbase = base;
    for (int k = 0; k < wv; ++k) wbase += wsum[k];
    if (m) {
      int pos = wbase + __popcll(bal & ((1ull << lane) - 1ull));
      list[e * T_TOK + pos] = i >> 1;
      listw[e * T_TOK + pos] = tok_w[i];
    }
    __syncthreads();
    if (tid == 0) {
      int s = 0;
#pragma unroll
      for (int k = 0; k < 16; ++k) s += wsum[k];
      base += s;
    }
    __syncthreads();
  }
  if (tid == 0) cursor[e] = base;
}

__global__ void moe_preduce(const float* __restrict__ pbuf, float* __restrict__ probs_sum) {
  const int e = blockIdx.x;
  float s = 0.0f;
  for (int t = threadIdx.x; t < T_TOK; t += 256) s += pbuf[(size_t)t * NEXP + e];
  __shared__ float red[4];
#pragma unroll
  for (int off = 32; off; off >>= 1) s += __shfl_down(s, off);
  if ((threadIdx.x & 63) == 0) red[threadIdx.x >> 6] = s;
  __syncthreads();
  if (threadIdx.x == 0) probs_sum[e] = red[0] + red[1] + red[2] + red[3];
}

// ---------------- offsets + tile map ----------------
__global__ void moe_offsets(const int* __restrict__ cursor, int* __restrict__ offs,
                            int* __restrict__ tile_e, int* __restrict__ tile_m,
                            int* __restrict__ meta) {
  if (threadIdx.x == 0 && blockIdx.x == 0) {
    int o = 0, t = 0;
    for (int e = 0; e < NEXP; ++e) {
      offs[e] = o;
      int ntl = (cursor[e] + BM - 1) / BM;
      for (int k = 0; k < ntl; ++k) { tile_e[t] = e; tile_m[t] = k; ++t; }
      o += ntl * BM;
    }
    offs[NEXP] = o;
    meta[0] = t;
  }
}

// ring-3 counted-vmcnt phase engine shared by fc1/fc2 (macro over source pointers)
#define PIPE_STAGE(Lbase, s, ktv)                                    \
  {                                                                  \
    char* Ld_ = (Lbase) + (s) * SLOTB + wv * 1024;                   \
    gl16(aS0 + (size_t)(ktv) * 64, Ld_);                             \
    gl16(aS1 + (size_t)(ktv) * 64, Ld_ + 4096);                      \
    gl16(bS0 + (size_t)(ktv) * 64, Ld_ + 8192);                      \
    gl16(bS1 + (size_t)(ktv) * 64, Ld_ + 12288);                     \
  }

// ---------------- fc1 (all experts): hbuf = gelu(X_e @ W1_e^T + b1) ----------------
__global__ __launch_bounds__(256, 3) void moe_fc1(
    const unsigned short* __restrict__ xb, const unsigned short* __restrict__ w1b,
    const float* __restrict__ b1, const int* __restrict__ list,
    const int* __restrict__ offs, const int* __restrict__ tile_e,
    const int* __restrict__ tile_m, const int* __restrict__ meta,
    unsigned short* __restrict__ hbuf, int cb, int ch) {
  const int bid = blockIdx.x;
  const int c = bid & 7;
  const int k = bid >> 3;
  const int tl = c * 17 + k % 17;
  const int nt = k / 17;
  if (tl >= meta[0]) return;
  const int e = tile_e[tl], mt = tile_m[tl];
  __shared__ __align__(16) char L[3 * SLOTB];
  const int tid = threadIdx.x, lane = tid & 63, wv = tid >> 6;
  const int wr = wv >> 1, wc = wv & 1;
  const int chunk = ((tid & 3) ^ ((tid >> 3) & 3)) << 4;   // inverse-swz source (bytes)
  const int r0 = tid >> 2;
  const int* le = list + e * T_TOK + mt * BM;
  int t0 = le[r0];       t0 = t0 < 0 ? 0 : t0;
  int t1 = le[64 + r0];  t1 = t1 < 0 ? 0 : t1;
  const char* aS0 = (const char*)(xb + (size_t)t0 * HID) + chunk;
  const char* aS1 = (const char*)(xb + (size_t)t1 * HID) + chunk;
  const char* bS0 = (const char*)(w1b + ((size_t)e * FFN_DIM + cb + nt * BM + r0) * HID) + chunk;
  const char* bS1 = (const char*)(w1b + ((size_t)e * FFN_DIM + cb + nt * BM + 64 + r0) * HID) + chunk;

  const int rsw = (((lane >> 4) ^ ((lane >> 1) & 3)) << 4);
  const int ra = (wr * 64 + (lane & 15)) * 64;
  const int rb = 8192 + (wc * 64 + (lane & 15)) * 64;

  f32x4 acc[4][4] = {};
  const int nK = HID / 32;   // 32

  PIPE_STAGE(L, 0, 0);
  PIPE_STAGE(L, 1, 1);
  asm volatile("s_waitcnt vmcnt(4)" ::: "memory");
  __builtin_amdgcn_s_barrier();
  __builtin_amdgcn_sched_barrier(0);

  int scur = 0, s2 = 2;
  for (int kt = 0; kt < nK; ++kt) {
    const char* Ab = L + scur * SLOTB;
    bf16x8 afr[4], bfr[4];
#pragma unroll
    for (int m = 0; m < 4; ++m) afr[m] = *(const bf16x8*)(Ab + ra + m * 1024 + rsw);
#pragma unroll
    for (int n = 0; n < 4; ++n) bfr[n] = *(const bf16x8*)(Ab + rb + n * 1024 + rsw);
    const bool stg = (kt + 2 < nK);
    if (stg) PIPE_STAGE(L, s2, kt + 2);
    __builtin_amdgcn_s_setprio(1);
#pragma unroll
    for (int m = 0; m < 4; ++m)
#pragma unroll
      for (int n = 0; n < 4; ++n)
        acc[m][n] = __builtin_amdgcn_mfma_f32_16x16x32_bf16(afr[m], bfr[n], acc[m][n], 0, 0, 0);
    __builtin_amdgcn_s_setprio(0);
    if (stg) {
      asm volatile("s_waitcnt vmcnt(4)" ::: "memory");   // keep this phase's 4 in flight
    } else {
      asm volatile("s_waitcnt vmcnt(0)" ::: "memory");   // tail: drain final slot (race fix)
    }
    __builtin_amdgcn_s_barrier();
    __builtin_amdgcn_sched_barrier(0);
    scur = (scur == 2) ? 0 : scur + 1;
    s2 = (s2 == 2) ? 0 : s2 + 1;
  }

  const float* b1e = b1 + (size_t)e * FFN_DIM + cb + nt * BM;
  const size_t rbase = (size_t)(offs[e] + mt * BM);
#pragma unroll
  for (int n = 0; n < 4; ++n) {
    int cl = wc * 64 + n * 16 + (lane & 15);
    float bias = b1e[cl];
#pragma unroll
    for (int m = 0; m < 4; ++m)
#pragma unroll
      for (int j = 0; j < 4; ++j) {
        int rl = wr * 64 + m * 16 + ((lane >> 4) << 2) + j;
        float v = acc[m][n][j] + bias;
        float g = 0.5f * v * (1.0f + erff(v * 0.70710678118654752f));
        hbuf[(rbase + rl) * ch + nt * BM + cl] = f2bf(g);
      }
  }
}

// ---------------- fc2 (all experts): out[tok] += w * (hbuf @ W2_e^T + b2) ----------------
__global__ __launch_bounds__(256, 3) void moe_fc2(
    const unsigned short* __restrict__ hbuf, const unsigned short* __restrict__ w2b,
    const float* __restrict__ b2, const int* __restrict__ list, const float* __restrict__ listw,
    const int* __restrict__ offs, const int* __restrict__ tile_e,
    const int* __restrict__ tile_m, const int* __restrict__ meta,
    float* __restrict__ out, int cb, int ch) {
  const int bid = blockIdx.x;
  const int c = bid & 7;
  const int k = bid >> 3;
  const int tl = c * 17 + (k >> 3);
  const int nt = k & 7;
  if (tl >= meta[0]) return;
  const int e = tile_e[tl], mt = tile_m[tl];
  const int z = blockIdx.z;
  __shared__ __align__(16) char L[3 * SLOTB];
  const int tid = threadIdx.x, lane = tid & 63, wv = tid >> 6;
  const int wr = wv >> 1, wc = wv & 1;
  const int chunk = ((tid & 3) ^ ((tid >> 3) & 3)) << 4;
  const int r0 = tid >> 2;
  const size_t rbase = (size_t)(offs[e] + mt * BM);
  const size_t koffb = (size_t)z * (ch / 2) * 2;   // bytes into K
  const char* aS0 = (const char*)(hbuf + (rbase + r0) * ch) + koffb + chunk;
  const char* aS1 = (const char*)(hbuf + (rbase + 64 + r0) * ch) + koffb + chunk;
  const char* bS0 = (const char*)(w2b + ((size_t)e * HID + nt * BM + r0) * FFN_DIM + cb) + koffb + chunk;
  const char* bS1 = (const char*)(w2b + ((size_t)e * HID + nt * BM + 64 + r0) * FFN_DIM + cb) + koffb + chunk;

  const int rsw = (((lane >> 4) ^ ((lane >> 1) & 3)) << 4);
  const int ra = (wr * 64 + (lane & 15)) * 64;
  const int rb = 8192 + (wc * 64 + (lane & 15)) * 64;

  f32x4 acc[4][4] = {};
  const int nK = (ch / 2) / 32;   // 64

  PIPE_STAGE(L, 0, 0);
  PIPE_STAGE(L, 1, 1);
  asm volatile("s_waitcnt vmcnt(4)" ::: "memory");
  __builtin_amdgcn_s_barrier();
  __builtin_amdgcn_sched_barrier(0);

  int scur = 0, s2 = 2;
  for (int kt = 0; kt < nK; ++kt) {
    const char* Ab = L + scur * SLOTB;
    bf16x8 afr[4], bfr[4];
#pragma unroll
    for (int m = 0; m < 4; ++m) afr[m] = *(const bf16x8*)(Ab + ra + m * 1024 + rsw);
#pragma unroll
    for (int n = 0; n < 4; ++n) bfr[n] = *(const bf16x8*)(Ab + rb + n * 1024 + rsw);
    const bool stg = (kt + 2 < nK);
    if (stg) PIPE_STAGE(L, s2, kt + 2);
    __builtin_amdgcn_s_setprio(1);
#pragma unroll
    for (int m = 0; m < 4; ++m)
#pragma unroll
      for (int n = 0; n < 4; ++n)
        acc[m][n] = __builtin_amdgcn_mfma_f32_16x16x32_bf16(afr[m], bfr[n], acc[m][n], 0, 0, 0);
    __builtin_amdgcn_s_setprio(0);
    if (stg) {
      asm volatile("s_waitcnt vmcnt(4)" ::: "memory");
    } else {
      asm volatile("s_waitcnt vmcnt(0)" ::: "memory");   // tail: drain final slot (race fix)
    }
    __builtin_amdgcn_s_barrier();
    __builtin_amdgcn_sched_barrier(0);
    scur = (scur == 2) ? 0 : scur + 1;
    s2 = (s2 == 2) ? 0 : s2 + 1;
  }

  const int* le = list + e * T_TOK + mt * BM;
  const float* lw = listw + e * T_TOK + mt * BM;
  const float* b2e = b2 + (size_t)e * HID + nt * BM;
  const bool addb = (cb == 0) && (z == 0);
#pragma unroll
  for (int m = 0; m < 4; ++m)
#pragma unroll
    for (int j = 0; j < 4; ++j) {
      int rl = wr * 64 + m * 16 + ((lane >> 4) << 2) + j;
      int tok = le[rl];
      if (tok < 0) continue;
      float wgt = lw[rl];
      float* orow = out + (size_t)tok * HID + nt * BM;
#pragma unroll
      for (int n = 0; n < 4; ++n) {
        int cl = wc * 64 + n * 16 + (lane & 15);
        float v = acc[m][n][j];
        if (addb) v += b2e[cl];
        atomicAdd(orow + cl, wgt * v);
      }
    }
}

__global__ void moe_finalize(const float* __restrict__ probs_sum, const int* __restrict__ cursor,
                             float* __restrict__ out_aux) {
  if (threadIdx.x == 0 && blockIdx.x == 0) {
    float a = 0.0f;
    for (int e = 0; e < NEXP; ++e)
      a += (probs_sum[e] / (float)T_TOK) * ((float)cursor[e] / (float)(T_TOK * 2));
    out_aux[0] = 0.01f * (float)NEXP * a;
  }
}

extern "C" void kernel_launch(void* const* d_in, const int* in_sizes, int n_in,
                              void* d_out, int out_size, void* d_ws, size_t ws_size,
                              hipStream_t stream) {
  const float* x  = (const float*)d_in[0];
  const float* rw = (const float*)d_in[1];
  const float* w1 = (const float*)d_in[2];
  const float* b1 = (const float*)d_in[3];
  const float* w2 = (const float*)d_in[4];
  const float* b2 = (const float*)d_in[5];
  float* out = (float*)d_out;

  char* ws = (char*)d_ws;
  float* probs_sum = (float*)(ws + 0);
  int*   cursor    = (int*)(ws + 256);
  int*   meta      = (int*)(ws + 512);
  int*   offs      = (int*)(ws + 1024);
  int*   tile_e    = (int*)(ws + 2048);
  int*   tile_m    = (int*)(ws + 4096);
  int*   tok_idx   = (int*)(ws + 8192);
  float* tok_w     = (float*)(ws + 8192 + 65536);
  int*   list      = (int*)(ws + 8192 + 131072);
  float* listw     = (float*)(ws + 8192 + 393216);
  float* pbuf      = (float*)(ws + 8192 + 655360);
  unsigned short* xb   = (unsigned short*)(ws + 1048576);
  unsigned short* w1be = (unsigned short*)(ws + 17825792);
  unsigned short* w2be = (unsigned short*)(ws + 84934656);
  const size_t HBUF_OFF = 152043520;
  unsigned short* hbuf = (unsigned short*)(ws + HBUF_OFF);

  int CH = 4096;
  while (CH > 1024 && HBUF_OFF + (size_t)(MAX_TILES * BM) * CH * 2 > ws_size) CH >>= 1;

  hipMemsetAsync(d_out, 0, (size_t)out_size * sizeof(float), stream);
  hipMemsetAsync(ws + 8192 + 131072, 0xFF, 262144, stream);   // list = -1 sentinels

  moe_cvt_w<<<dim3(16384, 2), 256, 0, stream>>>(w1, w2, w1be, w2be);
  moe_router<<<T_TOK / 4, 256, 0, stream>>>(x, rw, tok_idx, tok_w, pbuf, xb);
  moe_scatter<<<NEXP, 1024, 0, stream>>>(tok_idx, tok_w, cursor, list, listw);
  moe_preduce<<<NEXP, 256, 0, stream>>>(pbuf, probs_sum);
  moe_offsets<<<1, 1, 0, stream>>>(cursor, offs, tile_e, tile_m, meta);

  for (int cb = 0; cb < FFN_DIM; cb += CH) {
    moe_fc1<<<MAX_TILES * (CH / BM), 256, 0, stream>>>(
        xb, w1be, b1, list, offs, tile_e, tile_m, meta, hbuf, cb, CH);
    moe_fc2<<<dim3(MAX_TILES * 8, 1, 2), 256, 0, stream>>>(
        hbuf, w2be, b2, list, listw, offs, tile_e, tile_m, meta, out, cb, CH);
  }
  moe_finalize<<<1, 64, 0, stream>>>(probs_sum, cursor, out + (size_t)T_TOK * HID);
}

// Round 9
// 607.579 us; speedup vs baseline: 1.0943x; 1.0943x over previous
//
#include <hip/hip_runtime.h>
#include <math.h>

#define T_TOK 8192
#define HID 1024
#define FFN_DIM 4096
#define NEXP 8
#define BM 128
#define MAX_TILES 136   // 8 * 17

typedef __attribute__((ext_vector_type(8))) __bf16 bf16x8;
typedef __attribute__((ext_vector_type(8))) unsigned short ushort8;
typedef __attribute__((ext_vector_type(4))) float f32x4;

static __device__ __forceinline__ unsigned short f2bf(float f) {
  unsigned u = __builtin_bit_cast(unsigned, f);
  u += 0x7FFFu + ((u >> 16) & 1u);
  return (unsigned short)(u >> 16);
}

static __device__ __forceinline__ void gl16(const void* g, void* l) {
  __builtin_amdgcn_global_load_lds((const __attribute__((address_space(1))) unsigned int*)g,
                                   (__attribute__((address_space(3))) unsigned int*)l,
                                   16, 0, 0);
}

static __device__ __forceinline__ ushort8 cvt8(const float* p) {
  float4 a = *(const float4*)p, b = *(const float4*)(p + 4);
  ushort8 o;
  o[0] = f2bf(a.x); o[1] = f2bf(a.y); o[2] = f2bf(a.z); o[3] = f2bf(a.w);
  o[4] = f2bf(b.x); o[5] = f2bf(b.y); o[6] = f2bf(b.z); o[7] = f2bf(b.w);
  return o;
}

// ---------------- weight conversion ----------------
__global__ void moe_cvt_w(const float* __restrict__ w1, const float* __restrict__ w2,
                          unsigned short* __restrict__ w1b, unsigned short* __restrict__ w2b) {
  size_t i = ((size_t)blockIdx.x * 256 + threadIdx.x) * 8;
  if (blockIdx.y == 0) *(ushort8*)(w1b + i) = cvt8(w1 + i);
  else                 *(ushort8*)(w2b + i) = cvt8(w2 + i);
}

// ---------------- router: one wave per token, f64 dots, f32 softmax; also emits xb ----------------
__global__ void moe_router(const float* __restrict__ x, const float* __restrict__ rw,
                           int* __restrict__ tok_idx, float* __restrict__ tok_w,
                           float* __restrict__ pbuf, unsigned short* __restrict__ xb) {
  int t = blockIdx.x * 4 + (threadIdx.x >> 6);
  int lane = threadIdx.x & 63;
  const float* xr = x + (size_t)t * HID;
  unsigned short* xbr = xb + (size_t)t * HID;
  double acc[NEXP];
#pragma unroll
  for (int e = 0; e < NEXP; ++e) acc[e] = 0.0;
  for (int i = 0; i < HID / 64; ++i) {
    float xv = xr[lane + 64 * i];
    xbr[lane + 64 * i] = f2bf(xv);
#pragma unroll
    for (int e = 0; e < NEXP; ++e)
      acc[e] += (double)xv * (double)rw[e * HID + lane + 64 * i];
  }
#pragma unroll
  for (int off = 32; off; off >>= 1)
#pragma unroll
    for (int e = 0; e < NEXP; ++e) acc[e] += __shfl_xor(acc[e], off);
  if (lane == 0) {
    double m = acc[0];
#pragma unroll
    for (int e = 1; e < NEXP; ++e) m = acc[e] > m ? acc[e] : m;
    float pf[NEXP], s = 0.0f;
#pragma unroll
    for (int e = 0; e < NEXP; ++e) { pf[e] = expf((float)(acc[e] - m)); s += pf[e]; }
    int i0 = 0;
#pragma unroll
    for (int e = 1; e < NEXP; ++e) if (acc[e] > acc[i0]) i0 = e;
    int i1 = (i0 == 0) ? 1 : 0;
#pragma unroll
    for (int e = 0; e < NEXP; ++e) if (e != i0 && acc[e] > acc[i1]) i1 = e;
    float w0 = pf[i0], w1 = pf[i1], wsum = w0 + w1;
    tok_idx[2 * t] = i0; tok_idx[2 * t + 1] = i1;
    tok_w[2 * t] = w0 / wsum; tok_w[2 * t + 1] = w1 / wsum;
    float inv = 1.0f / s;
#pragma unroll
    for (int e = 0; e < NEXP; ++e) pbuf[(size_t)t * NEXP + e] = pf[e] * inv;
  }
}

// ---------------- deterministic compaction: one 1024-thread block per expert ----------------
// also emits inv[2t+j] = (e<<13)|pos for the combine kernel
__global__ void moe_scatter(const int* __restrict__ tok_idx,
                            int* __restrict__ cursor, int* __restrict__ list,
                            int* __restrict__ inv) {
  const int e = blockIdx.x;
  __shared__ int wsum[16];
  __shared__ int base;
  const int tid = threadIdx.x, lane = tid & 63, wv = tid >> 6;
  if (tid == 0) base = 0;
  __syncthreads();
  for (int c = 0; c < 2 * T_TOK; c += 1024) {
    int i = c + tid;
    int m = (tok_idx[i] == e) ? 1 : 0;
    unsigned long long bal = __ballot(m);
    if (lane == 0) wsum[wv] = __popcll(bal);
    __syncthreads();
    int wbase = base;
    for (int k = 0; k < wv; ++k) wbase += wsum[k];
    if (m) {
      int pos = wbase + __popcll(bal & ((1ull << lane) - 1ull));
      list[e * T_TOK + pos] = i >> 1;
      inv[i] = (e << 13) | pos;
    }
    __syncthreads();
    if (tid == 0) {
      int s = 0;
#pragma unroll
      for (int k = 0; k < 16; ++k) s += wsum[k];
      base += s;
    }
    __syncthreads();
  }
  if (tid == 0) cursor[e] = base;
}

__global__ void moe_preduce(const float* __restrict__ pbuf, float* __restrict__ probs_sum) {
  const int e = blockIdx.x;
  float s = 0.0f;
  for (int t = threadIdx.x; t < T_TOK; t += 256) s += pbuf[(size_t)t * NEXP + e];
  __shared__ float red[4];
#pragma unroll
  for (int off = 32; off; off >>= 1) s += __shfl_down(s, off);
  if ((threadIdx.x & 63) == 0) red[threadIdx.x >> 6] = s;
  __syncthreads();
  if (threadIdx.x == 0) probs_sum[e] = red[0] + red[1] + red[2] + red[3];
}

// ---------------- offsets + tile map ----------------
__global__ void moe_offsets(const int* __restrict__ cursor, int* __restrict__ offs,
                            int* __restrict__ tile_e, int* __restrict__ tile_m,
                            int* __restrict__ meta) {
  if (threadIdx.x == 0 && blockIdx.x == 0) {
    int o = 0, t = 0;
    for (int e = 0; e < NEXP; ++e) {
      offs[e] = o;
      int ntl = (cursor[e] + BM - 1) / BM;
      for (int k = 0; k < ntl; ++k) { tile_e[t] = e; tile_m[t] = k; ++t; }
      o += ntl * BM;
    }
    offs[NEXP] = o;
    meta[0] = t;
  }
}

// ---------------- fc1 (all experts): hbuf = gelu(X_e @ W1_e^T + b1) ----------------
// grid.x = MAX_TILES * (ch/BM); XCD-chunked: XCD c owns tiles [17c,17c+17), nt-major.
__global__ __launch_bounds__(256, 4) void moe_fc1(
    const unsigned short* __restrict__ xb, const unsigned short* __restrict__ w1b,
    const float* __restrict__ b1, const int* __restrict__ list,
    const int* __restrict__ offs, const int* __restrict__ tile_e,
    const int* __restrict__ tile_m, const int* __restrict__ meta,
    unsigned short* __restrict__ hbuf, int cb, int ch) {
  const int bid = blockIdx.x;
  const int c = bid & 7;
  const int k = bid >> 3;
  const int tl = c * 17 + k % 17;
  const int nt = k / 17;
  if (tl >= meta[0]) return;
  const int e = tile_e[tl], mt = tile_m[tl];
  __shared__ __align__(16) char As[BM * 128];
  __shared__ __align__(16) char Bs[BM * 128];
  const int tid = threadIdx.x, lane = tid & 63, wv = tid >> 6;
  const int wr = wv >> 1, wc = wv & 1;
  const int swz = ((lane & 7) ^ (lane >> 3)) << 4;
  const int rsub = lane >> 3;
  const int* le = list + e * T_TOK + mt * BM;
  const char* asrc[4]; const char* bsrc[4];
  char* adst[4]; char* bdst[4];
#pragma unroll
  for (int j = 0; j < 4; ++j) {
    int r = wv * 32 + j * 8 + rsub;
    int tok = le[r]; tok = tok < 0 ? 0 : tok;
    asrc[j] = (const char*)(xb + (size_t)tok * HID) + swz;
    bsrc[j] = (const char*)(w1b + ((size_t)e * FFN_DIM + cb + nt * BM + r) * HID) + swz;
    adst[j] = As + (wv * 32 + j * 8) * 128;
    bdst[j] = Bs + (wv * 32 + j * 8) * 128;
  }
  f32x4 acc[4][4] = {};
  for (int kt = 0; kt < 16; ++kt) {
    if (kt) __syncthreads();
#pragma unroll
    for (int j = 0; j < 4; ++j) {
      gl16(asrc[j] + kt * 128, adst[j]);
      gl16(bsrc[j] + kt * 128, bdst[j]);
    }
    __syncthreads();
#pragma unroll
    for (int kh = 0; kh < 2; ++kh) {
      bf16x8 afr[4], bfr[4];
      const int kb = kh * 64 + ((lane >> 4) << 4);
#pragma unroll
      for (int m = 0; m < 4; ++m) {
        int row = wr * 64 + m * 16 + (lane & 15);
        afr[m] = *(const bf16x8*)(As + row * 128 + (kb ^ ((row & 7) << 4)));
      }
#pragma unroll
      for (int n = 0; n < 4; ++n) {
        int col = wc * 64 + n * 16 + (lane & 15);
        bfr[n] = *(const bf16x8*)(Bs + col * 128 + (kb ^ ((col & 7) << 4)));
      }
#pragma unroll
      for (int m = 0; m < 4; ++m)
#pragma unroll
        for (int n = 0; n < 4; ++n)
          acc[m][n] = __builtin_amdgcn_mfma_f32_16x16x32_bf16(afr[m], bfr[n], acc[m][n], 0, 0, 0);
    }
  }
  const float* b1e = b1 + (size_t)e * FFN_DIM + cb + nt * BM;
  const size_t rbase = (size_t)(offs[e] + mt * BM);
#pragma unroll
  for (int n = 0; n < 4; ++n) {
    int cl = wc * 64 + n * 16 + (lane & 15);
    float bias = b1e[cl];
#pragma unroll
    for (int m = 0; m < 4; ++m)
#pragma unroll
      for (int j = 0; j < 4; ++j) {
        int rl = wr * 64 + m * 16 + ((lane >> 4) << 2) + j;
        float v = acc[m][n][j] + bias;
        float g = 0.5f * v * (1.0f + erff(v * 0.70710678118654752f));
        hbuf[(rbase + rl) * ch + nt * BM + cl] = f2bf(g);
      }
  }
}

// ---------------- fc2 (all experts): ybuf[slot] = hbuf @ W2_e^T + b2 (no atomics) ----------------
// grid.x = MAX_TILES * 8; XCD c owns tiles [17c,17c+17); 8 nt per A-panel consecutive.
__global__ __launch_bounds__(256, 4) void moe_fc2(
    const unsigned short* __restrict__ hbuf, const unsigned short* __restrict__ w2b,
    const float* __restrict__ b2, const int* __restrict__ offs,
    const int* __restrict__ tile_e, const int* __restrict__ tile_m,
    const int* __restrict__ meta, float* __restrict__ ybuf, int cb, int ch) {
  const int bid = blockIdx.x;
  const int c = bid & 7;
  const int k = bid >> 3;
  const int tl = c * 17 + (k >> 3);
  const int nt = k & 7;
  if (tl >= meta[0]) return;
  const int e = tile_e[tl], mt = tile_m[tl];
  __shared__ __align__(16) char As[BM * 128];
  __shared__ __align__(16) char Bs[BM * 128];
  const int tid = threadIdx.x, lane = tid & 63, wv = tid >> 6;
  const int wr = wv >> 1, wc = wv & 1;
  const int swz = ((lane & 7) ^ (lane >> 3)) << 4;
  const int rsub = lane >> 3;
  const size_t rbase = (size_t)(offs[e] + mt * BM);
  const char* asrc[4]; const char* bsrc[4];
  char* adst[4]; char* bdst[4];
#pragma unroll
  for (int j = 0; j < 4; ++j) {
    int r = wv * 32 + j * 8 + rsub;
    asrc[j] = (const char*)(hbuf + (rbase + r) * ch) + swz;
    bsrc[j] = (const char*)(w2b + ((size_t)e * HID + nt * BM + r) * FFN_DIM + cb) + swz;
    adst[j] = As + (wv * 32 + j * 8) * 128;
    bdst[j] = Bs + (wv * 32 + j * 8) * 128;
  }
  f32x4 acc[4][4] = {};
  const int nK = ch / 64;
  for (int kt = 0; kt < nK; ++kt) {
    if (kt) __syncthreads();
#pragma unroll
    for (int j = 0; j < 4; ++j) {
      gl16(asrc[j] + kt * 128, adst[j]);
      gl16(bsrc[j] + kt * 128, bdst[j]);
    }
    __syncthreads();
#pragma unroll
    for (int kh = 0; kh < 2; ++kh) {
      bf16x8 afr[4], bfr[4];
      const int kb = kh * 64 + ((lane >> 4) << 4);
#pragma unroll
      for (int m = 0; m < 4; ++m) {
        int row = wr * 64 + m * 16 + (lane & 15);
        afr[m] = *(const bf16x8*)(As + row * 128 + (kb ^ ((row & 7) << 4)));
      }
#pragma unroll
      for (int n = 0; n < 4; ++n) {
        int col = wc * 64 + n * 16 + (lane & 15);
        bfr[n] = *(const bf16x8*)(Bs + col * 128 + (kb ^ ((col & 7) << 4)));
      }
#pragma unroll
      for (int m = 0; m < 4; ++m)
#pragma unroll
        for (int n = 0; n < 4; ++n)
          acc[m][n] = __builtin_amdgcn_mfma_f32_16x16x32_bf16(afr[m], bfr[n], acc[m][n], 0, 0, 0);
    }
  }
  const float* b2e = b2 + (size_t)e * HID + nt * BM;
#pragma unroll
  for (int m = 0; m < 4; ++m)
#pragma unroll
    for (int j = 0; j < 4; ++j) {
      int rl = wr * 64 + m * 16 + ((lane >> 4) << 2) + j;
      float* yrow = ybuf + (rbase + rl) * HID + nt * BM;
#pragma unroll
      for (int n = 0; n < 4; ++n) {
        int cl = wc * 64 + n * 16 + (lane & 15);
        float v = acc[m][n][j];
        if (cb == 0) yrow[cl] = v + b2e[cl];   // unique writer per element
        else         yrow[cl] += v;            // accumulate across FFN chunks
      }
    }
}

// ---------------- combine: out[t] = w0*ybuf[slot0] + w1*ybuf[slot1] ----------------
// one token per block (256 thr x float4 = 1024 cols)
__global__ void moe_combine(const float* __restrict__ ybuf, const int* __restrict__ inv,
                            const float* __restrict__ tok_w, const int* __restrict__ offs,
                            float* __restrict__ out) {
  const int t = blockIdx.x;
  const int col = threadIdx.x * 4;
  int v0 = inv[2 * t], v1 = inv[2 * t + 1];
  size_t r0 = (size_t)(offs[v0 >> 13] + (v0 & 8191));
  size_t r1 = (size_t)(offs[v1 >> 13] + (v1 & 8191));
  float w0 = tok_w[2 * t], w1 = tok_w[2 * t + 1];
  float4 a = *(const float4*)(ybuf + r0 * HID + col);
  float4 b = *(const float4*)(ybuf + r1 * HID + col);
  float4 o;
  o.x = w0 * a.x + w1 * b.x;
  o.y = w0 * a.y + w1 * b.y;
  o.z = w0 * a.z + w1 * b.z;
  o.w = w0 * a.w + w1 * b.w;
  *(float4*)(out + (size_t)t * HID + col) = o;
}

__global__ void moe_finalize(const float* __restrict__ probs_sum, const int* __restrict__ cursor,
                             float* __restrict__ out_aux) {
  if (threadIdx.x == 0 && blockIdx.x == 0) {
    float a = 0.0f;
    for (int e = 0; e < NEXP; ++e)
      a += (probs_sum[e] / (float)T_TOK) * ((float)cursor[e] / (float)(T_TOK * 2));
    out_aux[0] = 0.01f * (float)NEXP * a;
  }
}

extern "C" void kernel_launch(void* const* d_in, const int* in_sizes, int n_in,
                              void* d_out, int out_size, void* d_ws, size_t ws_size,
                              hipStream_t stream) {
  const float* x  = (const float*)d_in[0];
  const float* rw = (const float*)d_in[1];
  const float* w1 = (const float*)d_in[2];
  const float* b1 = (const float*)d_in[3];
  const float* w2 = (const float*)d_in[4];
  const float* b2 = (const float*)d_in[5];
  float* out = (float*)d_out;

  char* ws = (char*)d_ws;
  float* probs_sum = (float*)(ws + 0);
  int*   cursor    = (int*)(ws + 256);
  int*   meta      = (int*)(ws + 512);
  int*   offs      = (int*)(ws + 1024);
  int*   tile_e    = (int*)(ws + 2048);
  int*   tile_m    = (int*)(ws + 4096);
  int*   tok_idx   = (int*)(ws + 8192);                 // 64 KB
  float* tok_w     = (float*)(ws + 8192 + 65536);       // 64 KB
  int*   list      = (int*)(ws + 8192 + 131072);        // 256 KB
  float* pbuf      = (float*)(ws + 8192 + 655360);      // 256 KB
  int*   inv       = (int*)(ws + 925696);               // 64 KB
  unsigned short* xb   = (unsigned short*)(ws + 1048576);     // 16.8 MB
  unsigned short* w1be = (unsigned short*)(ws + 17825792);    // 67.1 MB
  unsigned short* w2be = (unsigned short*)(ws + 84934656);    // 67.1 MB
  float* ybuf = (float*)(ws + 152043520);                     // 71.3 MB (17408 x 1024 f32)
  const size_t HBUF_OFF = 223346688;
  unsigned short* hbuf = (unsigned short*)(ws + HBUF_OFF);

  int CH = 4096;
  while (CH > 1024 && HBUF_OFF + (size_t)(MAX_TILES * BM) * CH * 2 > ws_size) CH >>= 1;

  hipMemsetAsync(ws + 8192 + 131072, 0xFF, 262144, stream);   // list = -1 sentinels

  moe_cvt_w<<<dim3(16384, 2), 256, 0, stream>>>(w1, w2, w1be, w2be);
  moe_router<<<T_TOK / 4, 256, 0, stream>>>(x, rw, tok_idx, tok_w, pbuf, xb);
  moe_scatter<<<NEXP, 1024, 0, stream>>>(tok_idx, cursor, list, inv);
  moe_preduce<<<NEXP, 256, 0, stream>>>(pbuf, probs_sum);
  moe_offsets<<<1, 1, 0, stream>>>(cursor, offs, tile_e, tile_m, meta);

  for (int cb = 0; cb < FFN_DIM; cb += CH) {
    moe_fc1<<<MAX_TILES * (CH / BM), 256, 0, stream>>>(
        xb, w1be, b1, list, offs, tile_e, tile_m, meta, hbuf, cb, CH);
    moe_fc2<<<MAX_TILES * 8, 256, 0, stream>>>(
        hbuf, w2be, b2, offs, tile_e, tile_m, meta, ybuf, cb, CH);
  }
  moe_combine<<<T_TOK, 256, 0, stream>>>(ybuf, inv, tok_w, offs, out);
  moe_finalize<<<1, 64, 0, stream>>>(probs_sum, cursor, out + (size_t)T_TOK * HID);
}

// Round 10
// 556.359 us; speedup vs baseline: 1.1951x; 1.0921x over previous
//
#include <hip/hip_runtime.h>
#include <math.h>

#define T_TOK 8192
#define HID 1024
#define FFN_DIM 4096
#define NEXP 8
#define BM 128
#define MAX_TILES 136   // 8 * 17

typedef __attribute__((ext_vector_type(8))) __bf16 bf16x8;
typedef __attribute__((ext_vector_type(8))) unsigned short ushort8;
typedef __attribute__((ext_vector_type(4))) float f32x4;

static __device__ __forceinline__ unsigned short f2bf(float f) {
  unsigned u = __builtin_bit_cast(unsigned, f);
  u += 0x7FFFu + ((u >> 16) & 1u);
  return (unsigned short)(u >> 16);
}

static __device__ __forceinline__ void gl16(const void* g, void* l) {
  __builtin_amdgcn_global_load_lds((const __attribute__((address_space(1))) unsigned int*)g,
                                   (__attribute__((address_space(3))) unsigned int*)l,
                                   16, 0, 0);
}

static __device__ __forceinline__ ushort8 cvt8(const float* p) {
  float4 a = *(const float4*)p, b = *(const float4*)(p + 4);
  ushort8 o;
  o[0] = f2bf(a.x); o[1] = f2bf(a.y); o[2] = f2bf(a.z); o[3] = f2bf(a.w);
  o[4] = f2bf(b.x); o[5] = f2bf(b.y); o[6] = f2bf(b.z); o[7] = f2bf(b.w);
  return o;
}

// ---------------- weight conversion ----------------
__global__ void moe_cvt_w(const float* __restrict__ w1, const float* __restrict__ w2,
                          unsigned short* __restrict__ w1b, unsigned short* __restrict__ w2b) {
  size_t i = ((size_t)blockIdx.x * 256 + threadIdx.x) * 8;
  if (blockIdx.y == 0) *(ushort8*)(w1b + i) = cvt8(w1 + i);
  else                 *(ushort8*)(w2b + i) = cvt8(w2 + i);
}

// ---------------- router: one wave per token, f64 dots, f32 softmax; also emits xb ----------------
__global__ void moe_router(const float* __restrict__ x, const float* __restrict__ rw,
                           int* __restrict__ tok_idx, float* __restrict__ tok_w,
                           float* __restrict__ pbuf, unsigned short* __restrict__ xb) {
  int t = blockIdx.x * 4 + (threadIdx.x >> 6);
  int lane = threadIdx.x & 63;
  const float* xr = x + (size_t)t * HID;
  unsigned short* xbr = xb + (size_t)t * HID;
  double acc[NEXP];
#pragma unroll
  for (int e = 0; e < NEXP; ++e) acc[e] = 0.0;
  for (int i = 0; i < HID / 64; ++i) {
    float xv = xr[lane + 64 * i];
    xbr[lane + 64 * i] = f2bf(xv);
#pragma unroll
    for (int e = 0; e < NEXP; ++e)
      acc[e] += (double)xv * (double)rw[e * HID + lane + 64 * i];
  }
#pragma unroll
  for (int off = 32; off; off >>= 1)
#pragma unroll
    for (int e = 0; e < NEXP; ++e) acc[e] += __shfl_xor(acc[e], off);
  if (lane == 0) {
    double m = acc[0];
#pragma unroll
    for (int e = 1; e < NEXP; ++e) m = acc[e] > m ? acc[e] : m;
    float pf[NEXP], s = 0.0f;
#pragma unroll
    for (int e = 0; e < NEXP; ++e) { pf[e] = expf((float)(acc[e] - m)); s += pf[e]; }
    int i0 = 0;
#pragma unroll
    for (int e = 1; e < NEXP; ++e) if (acc[e] > acc[i0]) i0 = e;
    int i1 = (i0 == 0) ? 1 : 0;
#pragma unroll
    for (int e = 0; e < NEXP; ++e) if (e != i0 && acc[e] > acc[i1]) i1 = e;
    float w0 = pf[i0], w1 = pf[i1], wsum = w0 + w1;
    tok_idx[2 * t] = i0; tok_idx[2 * t + 1] = i1;
    tok_w[2 * t] = w0 / wsum; tok_w[2 * t + 1] = w1 / wsum;
    float inv = 1.0f / s;
#pragma unroll
    for (int e = 0; e < NEXP; ++e) pbuf[(size_t)t * NEXP + e] = pf[e] * inv;
  }
}

// ---------------- deterministic compaction: one 1024-thread block per expert ----------------
__global__ void moe_scatter(const int* __restrict__ tok_idx,
                            int* __restrict__ cursor, int* __restrict__ list,
                            int* __restrict__ inv) {
  const int e = blockIdx.x;
  __shared__ int wsum[16];
  __shared__ int base;
  const int tid = threadIdx.x, lane = tid & 63, wv = tid >> 6;
  if (tid == 0) base = 0;
  __syncthreads();
  for (int c = 0; c < 2 * T_TOK; c += 1024) {
    int i = c + tid;
    int m = (tok_idx[i] == e) ? 1 : 0;
    unsigned long long bal = __ballot(m);
    if (lane == 0) wsum[wv] = __popcll(bal);
    __syncthreads();
    int wbase = base;
    for (int k = 0; k < wv; ++k) wbase += wsum[k];
    if (m) {
      int pos = wbase + __popcll(bal & ((1ull << lane) - 1ull));
      list[e * T_TOK + pos] = i >> 1;
      inv[i] = (e << 13) | pos;
    }
    __syncthreads();
    if (tid == 0) {
      int s = 0;
#pragma unroll
      for (int k = 0; k < 16; ++k) s += wsum[k];
      base += s;
    }
    __syncthreads();
  }
  if (tid == 0) cursor[e] = base;
}

__global__ void moe_preduce(const float* __restrict__ pbuf, float* __restrict__ probs_sum) {
  const int e = blockIdx.x;
  float s = 0.0f;
  for (int t = threadIdx.x; t < T_TOK; t += 256) s += pbuf[(size_t)t * NEXP + e];
  __shared__ float red[4];
#pragma unroll
  for (int off = 32; off; off >>= 1) s += __shfl_down(s, off);
  if ((threadIdx.x & 63) == 0) red[threadIdx.x >> 6] = s;
  __syncthreads();
  if (threadIdx.x == 0) probs_sum[e] = red[0] + red[1] + red[2] + red[3];
}

// ---------------- offsets + tile map ----------------
__global__ void moe_offsets(const int* __restrict__ cursor, int* __restrict__ offs,
                            int* __restrict__ tile_e, int* __restrict__ tile_m,
                            int* __restrict__ meta) {
  if (threadIdx.x == 0 && blockIdx.x == 0) {
    int o = 0, t = 0;
    for (int e = 0; e < NEXP; ++e) {
      offs[e] = o;
      int ntl = (cursor[e] + BM - 1) / BM;
      for (int k = 0; k < ntl; ++k) { tile_e[t] = e; tile_m[t] = k; ++t; }
      o += ntl * BM;
    }
    offs[NEXP] = o;
    meta[0] = t;
  }
}

// ---------------- fc1 (all experts): hbuf = gelu(X_e @ W1_e^T + b1) ----------------
// XCD c owns tiles [17c,17c+17); super-blocks of (8 tiles x 8 nt) -> A ws 2MB + B ws 2MB in L2.
// tg outer / ng inner: A-panels of a tile-group stay resident across its 4 nt-groups.
__global__ __launch_bounds__(256, 4) void moe_fc1(
    const unsigned short* __restrict__ xb, const unsigned short* __restrict__ w1b,
    const float* __restrict__ b1, const int* __restrict__ list,
    const int* __restrict__ offs, const int* __restrict__ tile_e,
    const int* __restrict__ tile_m, const int* __restrict__ meta,
    unsigned short* __restrict__ hbuf, int cb, int ch) {
  const int ntc = ch / BM;
  const int c = blockIdx.x & 7;
  int q = blockIdx.x >> 3;            // [0, 17*ntc)
  int tl, nt;
  if (q < 8 * ntc) {
    int ng = q >> 6, r = q & 63;
    tl = c * 17 + (r & 7);       nt = (ng << 3) + (r >> 3);
  } else if (q < 16 * ntc) {
    q -= 8 * ntc;
    int ng = q >> 6, r = q & 63;
    tl = c * 17 + 8 + (r & 7);   nt = (ng << 3) + (r >> 3);
  } else {
    q -= 16 * ntc;
    tl = c * 17 + 16;            nt = q;
  }
  if (tl >= meta[0]) return;
  const int e = tile_e[tl], mt = tile_m[tl];
  __shared__ __align__(16) char As[BM * 128];
  __shared__ __align__(16) char Bs[BM * 128];
  const int tid = threadIdx.x, lane = tid & 63, wv = tid >> 6;
  const int wr = wv >> 1, wc = wv & 1;
  const int swz = ((lane & 7) ^ (lane >> 3)) << 4;
  const int rsub = lane >> 3;
  const int* le = list + e * T_TOK + mt * BM;
  const char* asrc[4]; const char* bsrc[4];
  char* adst[4]; char* bdst[4];
#pragma unroll
  for (int j = 0; j < 4; ++j) {
    int r = wv * 32 + j * 8 + rsub;
    int tok = le[r]; tok = tok < 0 ? 0 : tok;
    asrc[j] = (const char*)(xb + (size_t)tok * HID) + swz;
    bsrc[j] = (const char*)(w1b + ((size_t)e * FFN_DIM + cb + nt * BM + r) * HID) + swz;
    adst[j] = As + (wv * 32 + j * 8) * 128;
    bdst[j] = Bs + (wv * 32 + j * 8) * 128;
  }
  f32x4 acc[4][4] = {};
  for (int kt = 0; kt < 16; ++kt) {
    if (kt) __syncthreads();
#pragma unroll
    for (int j = 0; j < 4; ++j) {
      gl16(asrc[j] + kt * 128, adst[j]);
      gl16(bsrc[j] + kt * 128, bdst[j]);
    }
    __syncthreads();
#pragma unroll
    for (int kh = 0; kh < 2; ++kh) {
      bf16x8 afr[4], bfr[4];
      const int kb = kh * 64 + ((lane >> 4) << 4);
#pragma unroll
      for (int m = 0; m < 4; ++m) {
        int row = wr * 64 + m * 16 + (lane & 15);
        afr[m] = *(const bf16x8*)(As + row * 128 + (kb ^ ((row & 7) << 4)));
      }
#pragma unroll
      for (int n = 0; n < 4; ++n) {
        int col = wc * 64 + n * 16 + (lane & 15);
        bfr[n] = *(const bf16x8*)(Bs + col * 128 + (kb ^ ((col & 7) << 4)));
      }
#pragma unroll
      for (int m = 0; m < 4; ++m)
#pragma unroll
        for (int n = 0; n < 4; ++n)
          acc[m][n] = __builtin_amdgcn_mfma_f32_16x16x32_bf16(afr[m], bfr[n], acc[m][n], 0, 0, 0);
    }
  }
  const float* b1e = b1 + (size_t)e * FFN_DIM + cb + nt * BM;
  const size_t rbase = (size_t)(offs[e] + mt * BM);
  float bias[4];
#pragma unroll
  for (int n = 0; n < 4; ++n) bias[n] = b1e[wc * 64 + n * 16 + (lane & 15)];
  // m,j outer / n inner: the 4 stores per row are adjacent -> full 128B-line sectors
#pragma unroll
  for (int m = 0; m < 4; ++m)
#pragma unroll
    for (int j = 0; j < 4; ++j) {
      int rl = wr * 64 + m * 16 + ((lane >> 4) << 2) + j;
      unsigned short* hrow = hbuf + (rbase + rl) * ch + nt * BM;
#pragma unroll
      for (int n = 0; n < 4; ++n) {
        int cl = wc * 64 + n * 16 + (lane & 15);
        float v = acc[m][n][j] + bias[n];
        float g = 0.5f * v * (1.0f + erff(v * 0.70710678118654752f));
        hrow[cl] = f2bf(g);
      }
    }
}

// ---------------- fc2 (all experts): ybuf[slot] = hbuf @ W2_e^T + b2 (no atomics) ----------------
// grid.x = MAX_TILES * 8; XCD c owns tiles [17c,17c+17); 8 nt per A-panel consecutive.
__global__ __launch_bounds__(256, 4) void moe_fc2(
    const unsigned short* __restrict__ hbuf, const unsigned short* __restrict__ w2b,
    const float* __restrict__ b2, const int* __restrict__ offs,
    const int* __restrict__ tile_e, const int* __restrict__ tile_m,
    const int* __restrict__ meta, float* __restrict__ ybuf, int cb, int ch) {
  const int bid = blockIdx.x;
  const int c = bid & 7;
  const int k = bid >> 3;
  const int tl = c * 17 + (k >> 3);
  const int nt = k & 7;
  if (tl >= meta[0]) return;
  const int e = tile_e[tl], mt = tile_m[tl];
  __shared__ __align__(16) char As[BM * 128];
  __shared__ __align__(16) char Bs[BM * 128];
  const int tid = threadIdx.x, lane = tid & 63, wv = tid >> 6;
  const int wr = wv >> 1, wc = wv & 1;
  const int swz = ((lane & 7) ^ (lane >> 3)) << 4;
  const int rsub = lane >> 3;
  const size_t rbase = (size_t)(offs[e] + mt * BM);
  const char* asrc[4]; const char* bsrc[4];
  char* adst[4]; char* bdst[4];
#pragma unroll
  for (int j = 0; j < 4; ++j) {
    int r = wv * 32 + j * 8 + rsub;
    asrc[j] = (const char*)(hbuf + (rbase + r) * ch) + swz;
    bsrc[j] = (const char*)(w2b + ((size_t)e * HID + nt * BM + r) * FFN_DIM + cb) + swz;
    adst[j] = As + (wv * 32 + j * 8) * 128;
    bdst[j] = Bs + (wv * 32 + j * 8) * 128;
  }
  f32x4 acc[4][4] = {};
  const int nK = ch / 64;
  for (int kt = 0; kt < nK; ++kt) {
    if (kt) __syncthreads();
#pragma unroll
    for (int j = 0; j < 4; ++j) {
      gl16(asrc[j] + kt * 128, adst[j]);
      gl16(bsrc[j] + kt * 128, bdst[j]);
    }
    __syncthreads();
#pragma unroll
    for (int kh = 0; kh < 2; ++kh) {
      bf16x8 afr[4], bfr[4];
      const int kb = kh * 64 + ((lane >> 4) << 4);
#pragma unroll
      for (int m = 0; m < 4; ++m) {
        int row = wr * 64 + m * 16 + (lane & 15);
        afr[m] = *(const bf16x8*)(As + row * 128 + (kb ^ ((row & 7) << 4)));
      }
#pragma unroll
      for (int n = 0; n < 4; ++n) {
        int col = wc * 64 + n * 16 + (lane & 15);
        bfr[n] = *(const bf16x8*)(Bs + col * 128 + (kb ^ ((col & 7) << 4)));
      }
#pragma unroll
      for (int m = 0; m < 4; ++m)
#pragma unroll
        for (int n = 0; n < 4; ++n)
          acc[m][n] = __builtin_amdgcn_mfma_f32_16x16x32_bf16(afr[m], bfr[n], acc[m][n], 0, 0, 0);
    }
  }
  const float* b2e = b2 + (size_t)e * HID + nt * BM;
#pragma unroll
  for (int m = 0; m < 4; ++m)
#pragma unroll
    for (int j = 0; j < 4; ++j) {
      int rl = wr * 64 + m * 16 + ((lane >> 4) << 2) + j;
      float* yrow = ybuf + (rbase + rl) * HID + nt * BM;
#pragma unroll
      for (int n = 0; n < 4; ++n) {
        int cl = wc * 64 + n * 16 + (lane & 15);
        float v = acc[m][n][j];
        if (cb == 0) yrow[cl] = v + b2e[cl];
        else         yrow[cl] += v;
      }
    }
}

// ---------------- combine: out[t] = w0*ybuf[slot0] + w1*ybuf[slot1] ----------------
__global__ void moe_combine(const float* __restrict__ ybuf, const int* __restrict__ inv,
                            const float* __restrict__ tok_w, const int* __restrict__ offs,
                            float* __restrict__ out) {
  const int t = blockIdx.x;
  const int col = threadIdx.x * 4;
  int v0 = inv[2 * t], v1 = inv[2 * t + 1];
  size_t r0 = (size_t)(offs[v0 >> 13] + (v0 & 8191));
  size_t r1 = (size_t)(offs[v1 >> 13] + (v1 & 8191));
  float w0 = tok_w[2 * t], w1 = tok_w[2 * t + 1];
  float4 a = *(const float4*)(ybuf + r0 * HID + col);
  float4 b = *(const float4*)(ybuf + r1 * HID + col);
  float4 o;
  o.x = w0 * a.x + w1 * b.x;
  o.y = w0 * a.y + w1 * b.y;
  o.z = w0 * a.z + w1 * b.z;
  o.w = w0 * a.w + w1 * b.w;
  *(float4*)(out + (size_t)t * HID + col) = o;
}

__global__ void moe_finalize(const float* __restrict__ probs_sum, const int* __restrict__ cursor,
                             float* __restrict__ out_aux) {
  if (threadIdx.x == 0 && blockIdx.x == 0) {
    float a = 0.0f;
    for (int e = 0; e < NEXP; ++e)
      a += (probs_sum[e] / (float)T_TOK) * ((float)cursor[e] / (float)(T_TOK * 2));
    out_aux[0] = 0.01f * (float)NEXP * a;
  }
}

extern "C" void kernel_launch(void* const* d_in, const int* in_sizes, int n_in,
                              void* d_out, int out_size, void* d_ws, size_t ws_size,
                              hipStream_t stream) {
  const float* x  = (const float*)d_in[0];
  const float* rw = (const float*)d_in[1];
  const float* w1 = (const float*)d_in[2];
  const float* b1 = (const float*)d_in[3];
  const float* w2 = (const float*)d_in[4];
  const float* b2 = (const float*)d_in[5];
  float* out = (float*)d_out;

  char* ws = (char*)d_ws;
  float* probs_sum = (float*)(ws + 0);
  int*   cursor    = (int*)(ws + 256);
  int*   meta      = (int*)(ws + 512);
  int*   offs      = (int*)(ws + 1024);
  int*   tile_e    = (int*)(ws + 2048);
  int*   tile_m    = (int*)(ws + 4096);
  int*   tok_idx   = (int*)(ws + 8192);                 // 64 KB
  float* tok_w     = (float*)(ws + 8192 + 65536);       // 64 KB
  int*   list      = (int*)(ws + 8192 + 131072);        // 256 KB
  float* pbuf      = (float*)(ws + 8192 + 655360);      // 256 KB
  int*   inv       = (int*)(ws + 925696);               // 64 KB
  unsigned short* xb   = (unsigned short*)(ws + 1048576);     // 16.8 MB
  unsigned short* w1be = (unsigned short*)(ws + 17825792);    // 67.1 MB
  unsigned short* w2be = (unsigned short*)(ws + 84934656);    // 67.1 MB
  float* ybuf = (float*)(ws + 152043520);                     // 71.3 MB
  const size_t HBUF_OFF = 223346688;
  unsigned short* hbuf = (unsigned short*)(ws + HBUF_OFF);

  int CH = 4096;
  while (CH > 1024 && HBUF_OFF + (size_t)(MAX_TILES * BM) * CH * 2 > ws_size) CH >>= 1;

  hipMemsetAsync(ws + 8192 + 131072, 0xFF, 262144, stream);   // list = -1 sentinels

  moe_cvt_w<<<dim3(16384, 2), 256, 0, stream>>>(w1, w2, w1be, w2be);
  moe_router<<<T_TOK / 4, 256, 0, stream>>>(x, rw, tok_idx, tok_w, pbuf, xb);
  moe_scatter<<<NEXP, 1024, 0, stream>>>(tok_idx, cursor, list, inv);
  moe_preduce<<<NEXP, 256, 0, stream>>>(pbuf, probs_sum);
  moe_offsets<<<1, 1, 0, stream>>>(cursor, offs, tile_e, tile_m, meta);

  for (int cb = 0; cb < FFN_DIM; cb += CH) {
    moe_fc1<<<MAX_TILES * (CH / BM), 256, 0, stream>>>(
        xb, w1be, b1, list, offs, tile_e, tile_m, meta, hbuf, cb, CH);
    moe_fc2<<<MAX_TILES * 8, 256, 0, stream>>>(
        hbuf, w2be, b2, offs, tile_e, tile_m, meta, ybuf, cb, CH);
  }
  moe_combine<<<T_TOK, 256, 0, stream>>>(ybuf, inv, tok_w, offs, out);
  moe_finalize<<<1, 64, 0, stream>>>(probs_sum, cursor, out + (size_t)T_TOK * HID);
}